// Round 10
// baseline (252.925 us; speedup 1.0000x reference)
//
#include <hip/hip_runtime.h>
#include <hip/hip_bf16.h>

#define N_NODES 100000
#define N_EDGES 1250000
#define N_FEAT 128
#define NHID 64
#define NUM_GRAPHS 256
#define CAP 32              // bucket capacity; live in-deg ~ Poisson(6.25), P(>=32) ~ 0
#define ROLE_BLOCKS 952
#define AB_BLOCKS 1904      // 2*952: even=k1-role, odd=k3-role
#define ZERO_BLOCKS 98
#define A_GRID (AB_BLOCKS + ZERO_BLOCKS)   // 2002
#define ZERO_WORDS 216384   // cnt(100000) + degf(100000) + pooled(16384)
#define K1_SLOTS (ROLE_BLOCKS * 4)         // 3808 wave-slots per role

typedef __attribute__((ext_vector_type(8))) short short8;
typedef __attribute__((ext_vector_type(16))) float float16;
typedef __attribute__((ext_vector_type(4))) int int4v;

static __device__ __forceinline__ short f2bf(float x) {
    __hip_bfloat16 b = __float2bfloat16(x);
    return *reinterpret_cast<short*>(&b);
}
static __device__ __forceinline__ float bf2f(unsigned short s) {
    __hip_bfloat16 b = *reinterpret_cast<__hip_bfloat16*>(&s);
    return __bfloat162float(b);
}
static __device__ __forceinline__ int pk2(float a, float b) {
    unsigned lo = (unsigned short)f2bf(a);
    unsigned hi = (unsigned short)f2bf(b);
    return (int)(lo | (hi << 16));
}

// ---------------------------------------------------------------------------
// Kernel A: three independent block-roles fused for co-scheduling:
//   even blocks < 1904 : edge MLP (all-MFMA, pure streaming ea -> edge_w)
//   odd  blocks < 1904 : xw = x @ Wg (MFMA, bf16 store, NO dinv — deferred)
//   blocks >= 1904     : zero cnt/degf/pooled
// ---------------------------------------------------------------------------
__global__ __launch_bounds__(256) void kA(
    const float* __restrict__ ea, const float* __restrict__ W1,
    const float* __restrict__ b1, const float* __restrict__ W2,
    const float* __restrict__ b2, const float* __restrict__ W3,
    const float* __restrict__ b3, float* __restrict__ edge_w,
    const float* __restrict__ x, const float* __restrict__ Wg,
    unsigned short* __restrict__ xw, int* __restrict__ zbase)
{
    const int bid = blockIdx.x;
    const int lane = threadIdx.x & 63;
    const int l31 = lane & 31;
    const int h = lane >> 5;
    const int wid = threadIdx.x >> 6;

    if (bid >= AB_BLOCKS) {
        // ---- zero role
        int idx = (bid - AB_BLOCKS) * 256 + threadIdx.x;
        for (int i = idx; i < ZERO_WORDS; i += ZERO_BLOCKS * 256) zbase[i] = 0;
        return;
    }

    if (bid & 1) {
        // ---- k3 role: one 32-node chunk per wave-slot
        int slot = (bid >> 1) * 4 + wid;
        if (slot >= N_NODES / 32) return;

        short8 bw[8][2];
        #pragma unroll
        for (int kk = 0; kk < 8; ++kk)
            #pragma unroll
            for (int u = 0; u < 2; ++u)
                #pragma unroll
                for (int j = 0; j < 8; ++j)
                    bw[kk][u][j] = f2bf(Wg[(kk * 16 + 8 * h + j) * NHID + u * 32 + l31]);

        int base = slot * 32;
        const float* xrow = x + (size_t)(base + l31) * N_FEAT + 8 * h;

        float16 acc0, acc1;
        #pragma unroll
        for (int r = 0; r < 16; ++r) { acc0[r] = 0.0f; acc1[r] = 0.0f; }

        #pragma unroll
        for (int kk = 0; kk < 8; ++kk) {
            float4 p = *(const float4*)(xrow + kk * 16);
            float4 q = *(const float4*)(xrow + kk * 16 + 4);
            short8 af;
            af[0] = f2bf(p.x); af[1] = f2bf(p.y); af[2] = f2bf(p.z); af[3] = f2bf(p.w);
            af[4] = f2bf(q.x); af[5] = f2bf(q.y); af[6] = f2bf(q.z); af[7] = f2bf(q.w);
            acc0 = __builtin_amdgcn_mfma_f32_32x32x16_bf16(af, bw[kk][0], acc0, 0, 0, 0);
            acc1 = __builtin_amdgcn_mfma_f32_32x32x16_bf16(af, bw[kk][1], acc1, 0, 0, 0);
        }

        #pragma unroll
        for (int r = 0; r < 16; ++r) {
            int node = base + (r & 3) + 8 * (r >> 2) + 4 * h;
            xw[(size_t)node * NHID + l31] = (unsigned short)f2bf(acc0[r]);
            xw[(size_t)node * NHID + 32 + l31] = (unsigned short)f2bf(acc1[r]);
        }
        return;
    }

    // ---- k1 role: edge MLP, pure streaming (proven 42 µs structure)
    const int wslot = (bid >> 1) * 4 + wid;
    const float b3v = b3[0];

    short8 a1hi[2], a1lo[2];
    #pragma unroll
    for (int t = 0; t < 2; ++t)
        #pragma unroll
        for (int j = 0; j < 8; ++j) {
            int k = 8 * h + j;
            int m = t * 32 + l31;
            float v = (k < 5) ? W1[k * NHID + m] : ((k == 5) ? b1[m] : 0.0f);
            short hi = f2bf(v);
            a1hi[t][j] = hi;
            a1lo[t][j] = f2bf(v - bf2f((unsigned short)hi));
        }

    short8 afrag[2][4];
    #pragma unroll
    for (int t = 0; t < 2; ++t)
        #pragma unroll
        for (int kk = 0; kk < 4; ++kk)
            #pragma unroll
            for (int j = 0; j < 8; ++j) {
                int k = kk * 16 + h * 8 + j;
                afrag[t][kk][j] = f2bf(W2[k * NHID + t * 32 + l31]);
            }

    short8 a2b[2], bone;
    #pragma unroll
    for (int t = 0; t < 2; ++t)
        #pragma unroll
        for (int j = 0; j < 8; ++j)
            a2b[t][j] = (h == 0 && j == 0) ? f2bf(b2[t * 32 + l31]) : (short)0;
    #pragma unroll
    for (int j = 0; j < 8; ++j)
        bone[j] = (h == 0 && j == 0) ? f2bf(1.0f) : (short)0;

    float w3r[2][16];
    #pragma unroll
    for (int t = 0; t < 2; ++t)
        #pragma unroll
        for (int r = 0; r < 16; ++r)
            w3r[t][r] = W3[t * 32 + (r & 3) + 8 * (r >> 2) + 4 * h];

    const int NCHUNK = (N_EDGES + 31) / 32;   // 39063

    for (int chunk = wslot; chunk < NCHUNK; chunk += K1_SLOTS) {
        int e = chunk * 32 + l31;
        bool valid = e < N_EDGES;
        int ec = valid ? e : (N_EDGES - 1);

        short8 behi, belo;
        #pragma unroll
        for (int j = 0; j < 8; ++j) {
            float v = 0.0f;
            if (h == 0) {
                if (j < 5) v = ea[ec * 5 + j];
                else if (j == 5) v = 1.0f;
            }
            short hi = f2bf(v);
            behi[j] = hi;
            belo[j] = (h == 0 && j < 5) ? f2bf(v - bf2f((unsigned short)hi)) : (short)0;
        }

        float16 A1[2];
        #pragma unroll
        for (int t = 0; t < 2; ++t)
            #pragma unroll
            for (int r = 0; r < 16; ++r) A1[t][r] = 0.0f;
        #pragma unroll
        for (int t = 0; t < 2; ++t) {
            A1[t] = __builtin_amdgcn_mfma_f32_32x32x16_bf16(a1hi[t], behi, A1[t], 0, 0, 0);
            A1[t] = __builtin_amdgcn_mfma_f32_32x32x16_bf16(a1hi[t], belo, A1[t], 0, 0, 0);
            A1[t] = __builtin_amdgcn_mfma_f32_32x32x16_bf16(a1lo[t], behi, A1[t], 0, 0, 0);
        }

        short8 bf2v[4];
        #pragma unroll
        for (int kk = 0; kk < 4; ++kk) {
            float lv0, lv1, lv2, lv3, hv0, hv1, hv2, hv3;
            int o = 8 * (kk & 1);
            int t = kk >> 1;
            lv0 = fmaxf(A1[t][o + 0], 0.f); lv1 = fmaxf(A1[t][o + 1], 0.f);
            lv2 = fmaxf(A1[t][o + 2], 0.f); lv3 = fmaxf(A1[t][o + 3], 0.f);
            hv0 = fmaxf(A1[t][o + 4], 0.f); hv1 = fmaxf(A1[t][o + 5], 0.f);
            hv2 = fmaxf(A1[t][o + 6], 0.f); hv3 = fmaxf(A1[t][o + 7], 0.f);
            int p_lv0 = pk2(lv0, lv1), p_lv1 = pk2(lv2, lv3);
            int p_hv0 = pk2(hv0, hv1), p_hv1 = pk2(hv2, hv3);
            int send0 = h ? p_lv0 : p_hv0;
            int send1 = h ? p_lv1 : p_hv1;
            int r0 = __shfl_xor(send0, 32, 64);
            int r1 = __shfl_xor(send1, 32, 64);
            int4v fi;
            fi.x = h ? r0 : p_lv0;
            fi.y = h ? r1 : p_lv1;
            fi.z = h ? p_hv0 : r0;
            fi.w = h ? p_hv1 : r1;
            bf2v[kk] = __builtin_bit_cast(short8, fi);
        }

        float16 C0, C1;
        #pragma unroll
        for (int r = 0; r < 16; ++r) { C0[r] = 0.0f; C1[r] = 0.0f; }
        #pragma unroll
        for (int kk = 0; kk < 4; ++kk) {
            C0 = __builtin_amdgcn_mfma_f32_32x32x16_bf16(afrag[0][kk], bf2v[kk], C0, 0, 0, 0);
            C1 = __builtin_amdgcn_mfma_f32_32x32x16_bf16(afrag[1][kk], bf2v[kk], C1, 0, 0, 0);
        }
        C0 = __builtin_amdgcn_mfma_f32_32x32x16_bf16(a2b[0], bone, C0, 0, 0, 0);
        C1 = __builtin_amdgcn_mfma_f32_32x32x16_bf16(a2b[1], bone, C1, 0, 0, 0);

        float partial = 0.0f;
        #pragma unroll
        for (int r = 0; r < 16; ++r) {
            partial += fmaxf(C0[r], 0.0f) * w3r[0][r];
            partial += fmaxf(C1[r], 0.0f) * w3r[1][r];
        }
        float total = partial + __shfl_xor(partial, 32, 64);
        float w = fmaxf(total + b3v, 0.0f);

        if (h == 0 && valid) edge_w[e] = w;
    }
}

// ---------------------------------------------------------------------------
// kB: bucket-CSR placement. pos = cnt[col]++ ; degf[col] += w ; store rec.
// ---------------------------------------------------------------------------
__global__ void kB_place(const float* __restrict__ edge_w,
                         const int* __restrict__ eidx,
                         int* __restrict__ cnt, float* __restrict__ degf,
                         int2* __restrict__ recs) {
    int e = blockIdx.x * 256 + threadIdx.x;
    if (e >= N_EDGES) return;
    float w = edge_w[e];
    if (w <= 0.0f) return;
    int col = eidx[N_EDGES + e];
    int pos = atomicAdd(&cnt[col], 1);
    atomicAdd(&degf[col], w);
    if (pos < CAP) recs[(size_t)col * CAP + pos] = make_int2(eidx[e], __float_as_int(w));
}

// ---------------------------------------------------------------------------
// kC: rescale recs weights in place: w' = w * rsqrt(1+deg[row]) * rsqrt(1+deg[col]).
// Thread per bucket slot (100000*CAP).
// ---------------------------------------------------------------------------
__global__ void kC_rescale(const int* __restrict__ cnt, const float* __restrict__ degf,
                           int2* __restrict__ recs) {
    int idx = blockIdx.x * 256 + threadIdx.x;
    int col = idx >> 5;            // CAP = 32
    int slot = idx & 31;
    if (col >= N_NODES) return;
    if (slot < min(cnt[col], CAP)) {
        int2 r = recs[idx];
        float w = __int_as_float(r.y);
        float wp = w * rsqrtf(1.0f + degf[r.x]) * rsqrtf(1.0f + degf[col]);
        recs[idx].y = __float_as_int(wp);
    }
}

// ---------------------------------------------------------------------------
// kD: fused gather + relu + pool. One wave per 4 nodes; gathers 4-wide.
// Self term = xw[n] * dinv^2 (dinv^2 = 1/(1+deg)); edge weights pre-scaled.
// ---------------------------------------------------------------------------
__global__ __launch_bounds__(256) void kD_gather_pool(
    const int* __restrict__ cnt, const int2* __restrict__ recs,
    const unsigned short* __restrict__ xw, const float* __restrict__ degf,
    const float* __restrict__ bg, const int* __restrict__ batch,
    float* __restrict__ pooled)
{
    const int lane = threadIdx.x & 63;
    const int wv = blockIdx.x * 4 + (threadIdx.x >> 6);
    int n0 = wv * 4;
    if (n0 >= N_NODES) return;
    int n1 = min(n0 + 4, N_NODES);
    float bgl = bg[lane];
    float pacc = 0.0f;
    int curg = batch[n0];
    for (int n = n0; n < n1; ++n) {
        int g = batch[n];
        if (g != curg) {
            atomicAdd(&pooled[curg * NHID + lane], pacc);
            pacc = 0.0f;
            curg = g;
        }
        int m = min(cnt[n], CAP);
        const int2* rb = recs + (size_t)n * CAP;
        float dv = rsqrtf(1.0f + degf[n]);
        float acc = bf2f(xw[(size_t)n * NHID + lane]) * (dv * dv);   // self-loop
        int j = 0;
        for (; j + 4 <= m; j += 4) {
            int2 r0 = rb[j], r1 = rb[j + 1], r2 = rb[j + 2], r3 = rb[j + 3];
            float g0 = bf2f(xw[(size_t)r0.x * NHID + lane]);
            float g1 = bf2f(xw[(size_t)r1.x * NHID + lane]);
            float g2 = bf2f(xw[(size_t)r2.x * NHID + lane]);
            float g3 = bf2f(xw[(size_t)r3.x * NHID + lane]);
            acc = fmaf(__int_as_float(r0.y), g0, acc);
            acc = fmaf(__int_as_float(r1.y), g1, acc);
            acc = fmaf(__int_as_float(r2.y), g2, acc);
            acc = fmaf(__int_as_float(r3.y), g3, acc);
        }
        for (; j < m; ++j) {
            int2 r = rb[j];
            acc = fmaf(__int_as_float(r.y), bf2f(xw[(size_t)r.x * NHID + lane]), acc);
        }
        pacc += fmaxf(acc + bgl, 0.0f);
    }
    atomicAdd(&pooled[curg * NHID + lane], pacc);
}

// ---------------------------------------------------------------------------
// kE: z = relu(pooled @ W_b1 + b_b1); out = z @ W_b2 + b_b2.
// ---------------------------------------------------------------------------
__global__ __launch_bounds__(64) void kE_final(
    const float* __restrict__ pooled, const float* __restrict__ Wb1,
    const float* __restrict__ bb1, const float* __restrict__ Wb2,
    const float* __restrict__ bb2, float* __restrict__ out) {
    __shared__ float p[NHID];
    int lane = threadIdx.x;
    int g = blockIdx.x;
    p[lane] = pooled[g * NHID + lane];
    __syncthreads();
    float z = bb1[lane];
    #pragma unroll
    for (int k = 0; k < NHID; ++k) z += p[k] * Wb1[k * NHID + lane];
    z = fmaxf(z, 0.0f) * Wb2[lane];
    #pragma unroll
    for (int off = 32; off > 0; off >>= 1)
        z += __shfl_down(z, off, 64);
    if (lane == 0) out[g] = z + bb2[0];
}

// ---------------------------------------------------------------------------
extern "C" void kernel_launch(void* const* d_in, const int* in_sizes, int n_in,
                              void* d_out, int out_size, void* d_ws, size_t ws_size,
                              hipStream_t stream) {
    const float* x        = (const float*)d_in[0];
    const float* ea       = (const float*)d_in[1];
    const float* W_e1     = (const float*)d_in[2];
    const float* b_e1     = (const float*)d_in[3];
    const float* W_e2     = (const float*)d_in[4];
    const float* b_e2     = (const float*)d_in[5];
    const float* W_e3     = (const float*)d_in[6];
    const float* b_e3     = (const float*)d_in[7];
    const float* W_g      = (const float*)d_in[8];
    const float* b_g      = (const float*)d_in[9];
    const float* W_b1     = (const float*)d_in[10];
    const float* b_b1     = (const float*)d_in[11];
    const float* W_b2     = (const float*)d_in[12];
    const float* b_b2     = (const float*)d_in[13];
    const int*   eidx     = (const int*)d_in[14];
    const int*   batch    = (const int*)d_in[15];
    float* out = (float*)d_out;

    // workspace layout (4-byte words); cnt|degf|pooled = zero region @0.
    char* wsb = (char*)d_ws;
    int*   cnt    = (int*)wsb;                              // @0        100,000
    float* degf   = (float*)(wsb + 4 * 100000);             // @100000   100,000
    float* pooled = (float*)(wsb + 4 * 200000);             // @200000    16,384
    float* edge_w = (float*)(wsb + 4 * 216448);             //          1,250,000
    int2*  recs   = (int2*)(wsb + 4 * 1466496);             // 100,000*32 int2
    unsigned short* xw = (unsigned short*)(wsb + 4 * 7866496);  // 6,400,000 ushort

    kA<<<dim3(A_GRID), dim3(256), 0, stream>>>(
        ea, W_e1, b_e1, W_e2, b_e2, W_e3, b_e3, edge_w, x, W_g, xw, (int*)wsb);
    kB_place<<<dim3((N_EDGES + 255) / 256), dim3(256), 0, stream>>>(
        edge_w, eidx, cnt, degf, recs);
    kC_rescale<<<dim3((N_NODES * CAP) / 256), dim3(256), 0, stream>>>(cnt, degf, recs);
    kD_gather_pool<<<dim3(6250), dim3(256), 0, stream>>>(
        cnt, recs, xw, degf, b_g, batch, pooled);
    kE_final<<<dim3(NUM_GRAPHS), dim3(64), 0, stream>>>(pooled, W_b1, b_b1, W_b2, b_b2, out);
}

// Round 11
// 212.360 us; speedup vs baseline: 1.1910x; 1.1910x over previous
//
#include <hip/hip_runtime.h>
#include <hip/hip_bf16.h>

#define N_NODES 100000
#define N_EDGES 1250000
#define N_FEAT 128
#define NHID 64
#define NUM_GRAPHS 256
#define CAP 32        // bucket capacity; live in-deg ~ Poisson(6.25), P(>=32) ~ 0

typedef __attribute__((ext_vector_type(8))) short short8;
typedef __attribute__((ext_vector_type(16))) float float16;

static __device__ __forceinline__ short f2bf(float x) {
    __hip_bfloat16 b = __float2bfloat16(x);
    return *reinterpret_cast<short*>(&b);
}
static __device__ __forceinline__ float bf2f(unsigned short s) {
    __hip_bfloat16 b = *reinterpret_cast<__hip_bfloat16*>(&s);
    return __bfloat162float(b);
}
// rho: involution on [0,16): swaps 4-7 <-> 8-11
static __device__ __forceinline__ int rho(int s) {
    int r = s & 12;
    if (r == 4) return s + 4;
    if (r == 8) return s - 4;
    return s;
}
static __device__ __forceinline__ int uperm(int m) {
    return (m & ~15) | rho(m & 15);
}

// ---------------------------------------------------------------------------
// K1: edge MLP, all-MFMA, ZERO-SHUFFLE (R11).  Hidden units of layer1 are
// permuted by the involution rho in the A-frag/bias loads so that layer1's
// C-registers ARE layer2's B-fragments (lane-local): the old 8x shfl_xor
// half-wave exchange is deleted.  Since rho∘rho = id, layer2 A-frags are the
// ORIGINAL W2 order.  Pure streaming: ea -> edge_w, no atomics (R7 lesson).
// ---------------------------------------------------------------------------
__global__ __launch_bounds__(256) void k1_edge_mlp(
    const float* __restrict__ ea, const float* __restrict__ W1,
    const float* __restrict__ b1, const float* __restrict__ W2,
    const float* __restrict__ b2, const float* __restrict__ W3,
    const float* __restrict__ b3, float* __restrict__ edge_w)
{
    const int lane = threadIdx.x & 63;
    const int l31 = lane & 31;
    const int h = lane >> 5;
    const int wslot = blockIdx.x * 4 + (threadIdx.x >> 6);
    const int S = gridDim.x * 4;
    const float b3v = b3[0];

    // layer1 A-frags hi/lo with bias column, hidden index permuted by u():
    // A[m][k=8h+j] = W1[k][u(m)] (k<5), b1[u(m)] (k==5), else 0
    short8 a1hi[2], a1lo[2];
    #pragma unroll
    for (int t = 0; t < 2; ++t)
        #pragma unroll
        for (int j = 0; j < 8; ++j) {
            int k = 8 * h + j;
            int m = uperm(t * 32 + l31);
            float v = (k < 5) ? W1[k * NHID + m] : ((k == 5) ? b1[m] : 0.0f);
            short hi = f2bf(v);
            a1hi[t][j] = hi;
            a1lo[t][j] = f2bf(v - bf2f((unsigned short)hi));
        }

    // layer2 A-frags: ORIGINAL order (rho cancels): A[m][k=kk*16+8h+j] = W2[k][m]
    short8 afrag[2][4];
    #pragma unroll
    for (int t = 0; t < 2; ++t)
        #pragma unroll
        for (int kk = 0; kk < 4; ++kk)
            #pragma unroll
            for (int j = 0; j < 8; ++j) {
                int k = kk * 16 + h * 8 + j;
                afrag[t][kk][j] = f2bf(W2[k * NHID + t * 32 + l31]);
            }

    // layer2 bias K-group: A[m][k64] = b2[m]; B has 1.0 there
    short8 a2b[2], bone;
    #pragma unroll
    for (int t = 0; t < 2; ++t)
        #pragma unroll
        for (int j = 0; j < 8; ++j)
            a2b[t][j] = (h == 0 && j == 0) ? f2bf(b2[t * 32 + l31]) : (short)0;
    #pragma unroll
    for (int j = 0; j < 8; ++j)
        bone[j] = (h == 0 && j == 0) ? f2bf(1.0f) : (short)0;

    // W3 at layer2 C-layout rows
    float w3r[2][16];
    #pragma unroll
    for (int t = 0; t < 2; ++t)
        #pragma unroll
        for (int r = 0; r < 16; ++r)
            w3r[t][r] = W3[t * 32 + (r & 3) + 8 * (r >> 2) + 4 * h];

    const int NCHUNK = (N_EDGES + 31) / 32;   // 39063

    for (int chunk = wslot; chunk < NCHUNK; chunk += S) {
        int e = chunk * 32 + l31;
        bool valid = e < N_EDGES;
        int ec = valid ? e : (N_EDGES - 1);

        // ea B-frags hi/lo (bias 1.0 at j==5, h==0)
        short8 behi, belo;
        #pragma unroll
        for (int j = 0; j < 8; ++j) {
            float v = 0.0f;
            if (h == 0) {
                if (j < 5) v = ea[ec * 5 + j];
                else if (j == 5) v = 1.0f;
            }
            short hi = f2bf(v);
            behi[j] = hi;
            belo[j] = (h == 0 && j < 5) ? f2bf(v - bf2f((unsigned short)hi)) : (short)0;
        }

        // layer1 MFMAs (hi/lo split)
        float16 A1[2];
        #pragma unroll
        for (int t = 0; t < 2; ++t)
            #pragma unroll
            for (int r = 0; r < 16; ++r) A1[t][r] = 0.0f;
        #pragma unroll
        for (int t = 0; t < 2; ++t) {
            A1[t] = __builtin_amdgcn_mfma_f32_32x32x16_bf16(a1hi[t], behi, A1[t], 0, 0, 0);
            A1[t] = __builtin_amdgcn_mfma_f32_32x32x16_bf16(a1hi[t], belo, A1[t], 0, 0, 0);
            A1[t] = __builtin_amdgcn_mfma_f32_32x32x16_bf16(a1lo[t], behi, A1[t], 0, 0, 0);
        }

        // layer2 B-frags: LANE-LOCAL relu+pack (no shuffles!)
        short8 bf2v[4];
        #pragma unroll
        for (int kk = 0; kk < 4; ++kk) {
            int t = kk >> 1;
            int o = 8 * (kk & 1);
            #pragma unroll
            for (int j = 0; j < 8; ++j)
                bf2v[kk][j] = f2bf(fmaxf(A1[t][o + j], 0.0f));
        }

        // layer2 MFMAs (bias via 5th K-group)
        float16 C0, C1;
        #pragma unroll
        for (int r = 0; r < 16; ++r) { C0[r] = 0.0f; C1[r] = 0.0f; }
        #pragma unroll
        for (int kk = 0; kk < 4; ++kk) {
            C0 = __builtin_amdgcn_mfma_f32_32x32x16_bf16(afrag[0][kk], bf2v[kk], C0, 0, 0, 0);
            C1 = __builtin_amdgcn_mfma_f32_32x32x16_bf16(afrag[1][kk], bf2v[kk], C1, 0, 0, 0);
        }
        C0 = __builtin_amdgcn_mfma_f32_32x32x16_bf16(a2b[0], bone, C0, 0, 0, 0);
        C1 = __builtin_amdgcn_mfma_f32_32x32x16_bf16(a2b[1], bone, C1, 0, 0, 0);

        // layer3
        float partial = 0.0f;
        #pragma unroll
        for (int r = 0; r < 16; ++r) {
            partial += fmaxf(C0[r], 0.0f) * w3r[0][r];
            partial += fmaxf(C1[r], 0.0f) * w3r[1][r];
        }
        float total = partial + __shfl_xor(partial, 32, 64);
        float w = fmaxf(total + b3v, 0.0f);

        if (h == 0 && valid) edge_w[e] = w;
    }
}

// ---------------------------------------------------------------------------
// kB: bucket-CSR placement. ONE atomic (cnt++) + one 8B store per live edge.
// (degf atomic removed — dinv is computed from the bucket in kC_dinv.)
// ---------------------------------------------------------------------------
__global__ void kB_place(const float* __restrict__ edge_w,
                         const int* __restrict__ eidx,
                         int* __restrict__ cnt, int2* __restrict__ recs) {
    int e = blockIdx.x * 256 + threadIdx.x;
    if (e >= N_EDGES) return;
    float w = edge_w[e];
    if (w <= 0.0f) return;
    int col = eidx[N_EDGES + e];
    int pos = atomicAdd(&cnt[col], 1);
    if (pos < CAP) recs[(size_t)col * CAP + pos] = make_int2(eidx[e], __float_as_int(w));
}

// ---------------------------------------------------------------------------
// kC_dinv: per node, sum own bucket -> dinv[n] = rsqrt(1 + sum). No atomics.
// ---------------------------------------------------------------------------
__global__ void kC_dinv(const int* __restrict__ cnt, const int2* __restrict__ recs,
                        float* __restrict__ dinv) {
    int n = blockIdx.x * 256 + threadIdx.x;
    if (n >= N_NODES) return;
    int m = min(cnt[n], CAP);
    float s = 1.0f;
    for (int j = 0; j < m; ++j) s += __int_as_float(recs[(size_t)n * CAP + j].y);
    dinv[n] = rsqrtf(s);
}

// ---------------------------------------------------------------------------
// K3: xw[n] = x[n]@Wg (bf16, unnormalized — dinv applied in kD).
// One wave per 32 nodes.
// ---------------------------------------------------------------------------
__global__ __launch_bounds__(256) void k3_xw(
    const float* __restrict__ x, const float* __restrict__ Wg,
    unsigned short* __restrict__ xw)
{
    const int lane = threadIdx.x & 63;
    const int l31 = lane & 31;
    const int h = lane >> 5;
    const int wslot = blockIdx.x * 4 + (threadIdx.x >> 6);

    short8 bw[8][2];
    #pragma unroll
    for (int kk = 0; kk < 8; ++kk)
        #pragma unroll
        for (int u = 0; u < 2; ++u)
            #pragma unroll
            for (int j = 0; j < 8; ++j)
                bw[kk][u][j] = f2bf(Wg[(kk * 16 + 8 * h + j) * NHID + u * 32 + l31]);

    const int NC = N_NODES / 32;   // 3125
    for (int chunk = wslot; chunk < NC; chunk += gridDim.x * 4) {
        int base = chunk * 32;
        const float* xrow = x + (size_t)(base + l31) * N_FEAT + 8 * h;

        float16 acc0, acc1;
        #pragma unroll
        for (int r = 0; r < 16; ++r) { acc0[r] = 0.0f; acc1[r] = 0.0f; }

        #pragma unroll
        for (int kk = 0; kk < 8; ++kk) {
            float4 p = *(const float4*)(xrow + kk * 16);
            float4 q = *(const float4*)(xrow + kk * 16 + 4);
            short8 af;
            af[0] = f2bf(p.x); af[1] = f2bf(p.y); af[2] = f2bf(p.z); af[3] = f2bf(p.w);
            af[4] = f2bf(q.x); af[5] = f2bf(q.y); af[6] = f2bf(q.z); af[7] = f2bf(q.w);
            acc0 = __builtin_amdgcn_mfma_f32_32x32x16_bf16(af, bw[kk][0], acc0, 0, 0, 0);
            acc1 = __builtin_amdgcn_mfma_f32_32x32x16_bf16(af, bw[kk][1], acc1, 0, 0, 0);
        }

        #pragma unroll
        for (int r = 0; r < 16; ++r) {
            int node = base + (r & 3) + 8 * (r >> 2) + 4 * h;
            xw[(size_t)node * NHID + l31] = (unsigned short)f2bf(acc0[r]);
            xw[(size_t)node * NHID + 32 + l31] = (unsigned short)f2bf(acc1[r]);
        }
    }
}

// ---------------------------------------------------------------------------
// kD: fused gather + relu + pool. One wave per 4 nodes; gathers 4-wide.
// Edge normalization on the SCALAR side: dinv[row] is wave-uniform (record
// is uniform) -> s_load from L2-resident 400KB dinv. Self term = xw*dinv^2.
// ---------------------------------------------------------------------------
__global__ __launch_bounds__(256) void kD_gather_pool(
    const int* __restrict__ cnt, const int2* __restrict__ recs,
    const unsigned short* __restrict__ xw, const float* __restrict__ dinv,
    const float* __restrict__ bg, const int* __restrict__ batch,
    float* __restrict__ pooled)
{
    const int lane = threadIdx.x & 63;
    const int wv = blockIdx.x * 4 + (threadIdx.x >> 6);
    int n0 = wv * 4;
    if (n0 >= N_NODES) return;
    int n1 = min(n0 + 4, N_NODES);
    float bgl = bg[lane];
    float pacc = 0.0f;
    int curg = batch[n0];
    for (int n = n0; n < n1; ++n) {
        int g = batch[n];
        if (g != curg) {
            atomicAdd(&pooled[curg * NHID + lane], pacc);
            pacc = 0.0f;
            curg = g;
        }
        int m = min(cnt[n], CAP);
        const int2* rb = recs + (size_t)n * CAP;
        float dvn = dinv[n];
        float acc = bf2f(xw[(size_t)n * NHID + lane]) * dvn;   // self (x dvn again below)
        int j = 0;
        for (; j + 4 <= m; j += 4) {
            int2 r0 = rb[j], r1 = rb[j + 1], r2 = rb[j + 2], r3 = rb[j + 3];
            float w0 = __int_as_float(r0.y) * dinv[r0.x];
            float w1 = __int_as_float(r1.y) * dinv[r1.x];
            float w2 = __int_as_float(r2.y) * dinv[r2.x];
            float w3 = __int_as_float(r3.y) * dinv[r3.x];
            float g0 = bf2f(xw[(size_t)r0.x * NHID + lane]);
            float g1 = bf2f(xw[(size_t)r1.x * NHID + lane]);
            float g2 = bf2f(xw[(size_t)r2.x * NHID + lane]);
            float g3 = bf2f(xw[(size_t)r3.x * NHID + lane]);
            acc = fmaf(w0, g0, acc);
            acc = fmaf(w1, g1, acc);
            acc = fmaf(w2, g2, acc);
            acc = fmaf(w3, g3, acc);
        }
        for (; j < m; ++j) {
            int2 r = rb[j];
            float w = __int_as_float(r.y) * dinv[r.x];
            acc = fmaf(w, bf2f(xw[(size_t)r.x * NHID + lane]), acc);
        }
        pacc += fmaxf(acc * dvn + bgl, 0.0f);
    }
    atomicAdd(&pooled[curg * NHID + lane], pacc);
}

// ---------------------------------------------------------------------------
// kE: z = relu(pooled @ W_b1 + b_b1); out = z @ W_b2 + b_b2.
// ---------------------------------------------------------------------------
__global__ __launch_bounds__(64) void kE_final(
    const float* __restrict__ pooled, const float* __restrict__ Wb1,
    const float* __restrict__ bb1, const float* __restrict__ Wb2,
    const float* __restrict__ bb2, float* __restrict__ out) {
    __shared__ float p[NHID];
    int lane = threadIdx.x;
    int g = blockIdx.x;
    p[lane] = pooled[g * NHID + lane];
    __syncthreads();
    float z = bb1[lane];
    #pragma unroll
    for (int k = 0; k < NHID; ++k) z += p[k] * Wb1[k * NHID + lane];
    z = fmaxf(z, 0.0f) * Wb2[lane];
    #pragma unroll
    for (int off = 32; off > 0; off >>= 1)
        z += __shfl_down(z, off, 64);
    if (lane == 0) out[g] = z + bb2[0];
}

// ---------------------------------------------------------------------------
extern "C" void kernel_launch(void* const* d_in, const int* in_sizes, int n_in,
                              void* d_out, int out_size, void* d_ws, size_t ws_size,
                              hipStream_t stream) {
    const float* x        = (const float*)d_in[0];
    const float* ea       = (const float*)d_in[1];
    const float* W_e1     = (const float*)d_in[2];
    const float* b_e1     = (const float*)d_in[3];
    const float* W_e2     = (const float*)d_in[4];
    const float* b_e2     = (const float*)d_in[5];
    const float* W_e3     = (const float*)d_in[6];
    const float* b_e3     = (const float*)d_in[7];
    const float* W_g      = (const float*)d_in[8];
    const float* b_g      = (const float*)d_in[9];
    const float* W_b1     = (const float*)d_in[10];
    const float* b_b1     = (const float*)d_in[11];
    const float* W_b2     = (const float*)d_in[12];
    const float* b_b2     = (const float*)d_in[13];
    const int*   eidx     = (const int*)d_in[14];
    const int*   batch    = (const int*)d_in[15];
    float* out = (float*)d_out;

    // workspace (4-byte words); cnt|pooled = zero region @0.
    char* wsb = (char*)d_ws;
    int*   cnt    = (int*)wsb;                              // @0        100,000
    float* pooled = (float*)(wsb + 4 * 100000);             // @100000    16,384
    float* edge_w = (float*)(wsb + 4 * 116480);             //          1,250,000
    float* dinv   = (float*)(wsb + 4 * 1366480);            //            100,000
    int2*  recs   = (int2*)(wsb + 4 * 1466496);             // 100,000*32 int2
    unsigned short* xw = (unsigned short*)(wsb + 4 * 7866496);  // 6,400,000 ushort

    hipMemsetAsync(wsb, 0, 4 * 116384, stream);   // cnt + pooled

    k1_edge_mlp<<<dim3(2048), dim3(256), 0, stream>>>(
        ea, W_e1, b_e1, W_e2, b_e2, W_e3, b_e3, edge_w);
    kB_place<<<dim3((N_EDGES + 255) / 256), dim3(256), 0, stream>>>(
        edge_w, eidx, cnt, recs);
    kC_dinv<<<dim3((N_NODES + 255) / 256), dim3(256), 0, stream>>>(cnt, recs, dinv);
    k3_xw<<<dim3(782), dim3(256), 0, stream>>>(x, W_g, xw);
    kD_gather_pool<<<dim3(6250), dim3(256), 0, stream>>>(
        cnt, recs, xw, dinv, b_g, batch, pooled);
    kE_final<<<dim3(NUM_GRAPHS), dim3(64), 0, stream>>>(pooled, W_b1, b_b1, W_b2, b_b2, out);
}